// Round 8
// baseline (98.769 us; speedup 1.0000x reference)
//
#include <hip/hip_runtime.h>
#include <hip/hip_bf16.h>
#include <math.h>

typedef __attribute__((ext_vector_type(4))) float f32x4;
typedef __attribute__((ext_vector_type(8))) float f32x8;
typedef __bf16 bf16x8 __attribute__((ext_vector_type(8)));
typedef unsigned short u16;
typedef u16 u16x8 __attribute__((ext_vector_type(8)));
typedef void __attribute__((address_space(1))) * as1p;
typedef void __attribute__((address_space(3))) * as3p;

__device__ __forceinline__ unsigned short f2bf(float f) {
    union { float f; unsigned int u; } v; v.f = f;
    unsigned int u = v.u;
    u += 0x7fffu + ((u >> 16) & 1u);   // RNE
    return (unsigned short)(u >> 16);
}

__device__ __forceinline__ float bf2f(unsigned short b) {
    union { unsigned int u; float f; } v;
    v.u = ((unsigned int)b) << 16;
    return v.f;
}

__device__ __forceinline__ float fast_tanh(float v) {
    float vc = fminf(fmaxf(v, -15.f), 15.f);
    float e = __expf(2.f * vc);
    return (e - 1.f) / (e + 1.f);
}

// ---------- fused prepass: cvt x,h -> bf16  AND  3 weight transposes ----------
__global__ void prep_k(const float* __restrict__ x, const float* __restrict__ h,
                       const float* __restrict__ wz, const float* __restrict__ wrr,
                       const float* __restrict__ wh,
                       u16* __restrict__ xb, u16* __restrict__ hb,
                       u16* __restrict__ wzt, u16* __restrict__ wrt, u16* __restrict__ wht) {
    __shared__ float t[32][33];
    int bid = blockIdx.x;
    int tid = threadIdx.x;
    if (bid < 2048) {
        const int n4 = 16384 * 512 / 4;
        int i = bid * 256 + tid;
        const int stride = 2048 * 256;
        const float4* x4 = (const float4*)x;
        const float4* h4 = (const float4*)h;
        ushort4* xb4 = (ushort4*)xb;
        ushort4* hb4 = (ushort4*)hb;
        for (; i < n4; i += stride) {
            float4 v = x4[i];
            xb4[i] = make_ushort4(f2bf(v.x), f2bf(v.y), f2bf(v.z), f2bf(v.w));
            float4 w = h4[i];
            hb4[i] = make_ushort4(f2bf(w.x), f2bf(w.y), f2bf(w.z), f2bf(w.w));
        }
    } else {
        int b = bid - 2048;
        int z = b >> 9;                 // 0..2 selects weight
        int rem = b & 511;              // 16 x 32 tiles
        const float* src = (z == 0) ? wz : (z == 1) ? wrr : wh;
        u16* dst = (z == 0) ? wzt : (z == 1) ? wrt : wht;
        int n0 = (rem & 15) * 32;
        int k0 = (rem >> 4) * 32;
        int tx = tid & 31, ty = tid >> 5;
#pragma unroll
        for (int i = 0; i < 4; ++i)
            t[ty + i * 8][tx] = src[(size_t)(k0 + ty + i * 8) * 512 + n0 + tx];
        __syncthreads();
#pragma unroll
        for (int i = 0; i < 4; ++i)
            dst[(size_t)(n0 + ty + i * 8) * 1024 + k0 + tx] = f2bf(t[tx][ty + i * 8]);
    }
}

// ---------- BK=32 staging: 128x32 bf16 (8 KB), linear LDS dest, inverse-swizzled src ----------
__device__ __forceinline__ void stage32(const u16* g, int gstride, u16* region, int tid) {
#pragma unroll
    for (int i = 0; i < 2; ++i) {
        int ob = i * 4096 + ((tid >> 6) << 10);     // wave-uniform byte base
        int o = ob + ((tid & 63) << 4);
        int row = o >> 6;
        int cb = (o & 63) ^ ((row & 3) << 4);       // inverse swizzle (16B chunks)
        const u16* gp = g + (size_t)row * gstride + (cb >> 1);
        __builtin_amdgcn_global_load_lds((as1p)(void*)gp, (as3p)(void*)(region + (ob >> 1)), 16, 0, 0);
    }
}

__device__ __forceinline__ bf16x8 ld32(const u16* region, int r, int kb) {
    int byte = (r << 6) + (kb ^ ((r & 3) << 4));
    return *(const bf16x8*)((const char*)region + byte);
}

// ---------- one BK=32 step: 8 swizzled ds_read_b128 + 16 MFMA ----------
__device__ __forceinline__ void compute32(const u16* LA, const u16* LB,
                                          int wr, int wc, int l, f32x4 (&acc)[4][4]) {
    int fr = l & 15;
    int kbb = (l >> 4) << 4;
    bf16x8 a[4], b[4];
#pragma unroll
    for (int m = 0; m < 4; ++m)
        a[m] = ld32(LA, wr * 64 + m * 16 + fr, kbb);
#pragma unroll
    for (int n = 0; n < 4; ++n)
        b[n] = ld32(LB, wc * 64 + n * 16 + fr, kbb);
#pragma unroll
    for (int m = 0; m < 4; ++m)
#pragma unroll
        for (int n = 0; n < 4; ++n)
            acc[m][n] = __builtin_amdgcn_mfma_f32_16x16x32_bf16(a[m], b[n], acc[m][n], 0, 0, 0);
}

// ---------- 2-phase prefetch K-loop, BK=32, dbuf 32 KB total ----------
// buffer b: A at lds + b*8192, B at lds + b*8192 + 4096 (u16 offsets)
template<typename AF, typename BF>
__device__ __forceinline__ void kloop32(AF ga, BF gb, u16* lds, int tid,
                                        int wr, int wc, int l, f32x4 (&acc)[4][4]) {
    stage32(ga(0), 512, lds, tid);
    stage32(gb(0), 1024, lds + 4096, tid);
    __syncthreads();
#pragma unroll
    for (int i = 0; i < 31; ++i) {
        u16* nxt = lds + ((i + 1) & 1) * 8192;
        const u16* cur = lds + (i & 1) * 8192;
        stage32(ga(i + 1), 512, nxt, tid);          // issue next tile FIRST
        stage32(gb(i + 1), 1024, nxt + 4096, tid);
        compute32(cur, cur + 4096, wr, wc, l, acc); // latency hides under compute + other blocks
        __syncthreads();
    }
    compute32(lds + 8192, lds + 8192 + 4096, wr, wc, l, acc);
}

// ---------- scatter one 64-row half of acc into f32 [64][128] LDS tile ----------
// waves with wr==half hold rows [half*64, half*64+64)
__device__ __forceinline__ void scatter_half(float* tf, const f32x4 (&acc)[4][4],
                                             int wc, int l) {
    int colb = wc * 64;
    int rowb = (l >> 4) << 2;
#pragma unroll
    for (int n = 0; n < 4; ++n) {
        int col = colb + n * 16 + (l & 15);
#pragma unroll
        for (int m = 0; m < 4; ++m) {
            int row0 = rowb + m * 16;
#pragma unroll
            for (int r = 0; r < 4; ++r)
                tf[(row0 + r) * 128 + col] = acc[m][n][r];
        }
    }
}

// ================= gz: [X|H] @ Wz^T -> zgb bf16 =================
__global__ __launch_bounds__(256, 4) void gz_k(
    const u16* __restrict__ Xb, const u16* __restrict__ Hb, const u16* __restrict__ Wt,
    const float* __restrict__ ub, u16* __restrict__ zgb) {
    __shared__ u16 lds[2 * 8192];
    int tid = threadIdx.x;
    int l = tid & 63, w = tid >> 6;
    int wr = w >> 1, wc = w & 1;
    int swz = (blockIdx.x & 7) * 64 + (blockIdx.x >> 3);
    int mb = swz >> 2, nb = swz & 3;
    int m0 = mb * 128, n0 = nb * 128;
    f32x4 acc[4][4];
#pragma unroll
    for (int m = 0; m < 4; ++m)
#pragma unroll
        for (int n = 0; n < 4; ++n) acc[m][n] = (f32x4){0.f, 0.f, 0.f, 0.f};

    auto ga = [&](int t) -> const u16* {
        return (t < 16) ? (Xb + (size_t)m0 * 512 + t * 32)
                        : (Hb + (size_t)m0 * 512 + (t - 16) * 32);
    };
    auto gb = [&](int t) -> const u16* { return Wt + (size_t)n0 * 1024 + t * 32; };
    kloop32(ga, gb, lds, tid, wr, wc, l, acc);

    float* tf = (float*)lds;
#pragma unroll
    for (int half = 0; half < 2; ++half) {
        __syncthreads();
        if (wr == half) scatter_half(tf, acc, wc, l);
        __syncthreads();
#pragma unroll
        for (int it = 0; it < 4; ++it) {
            int chunk = it * 256 + tid;           // 64 rows x 16 groups
            int row = chunk >> 4;
            int c8 = (chunk & 15) << 3;
            f32x8 v8 = *(const f32x8*)&tf[row * 128 + c8];
            int gcol = n0 + c8;
            f32x8 ubv = *(const f32x8*)&ub[gcol];
            u16x8 o;
#pragma unroll
            for (int j = 0; j < 8; ++j)
                o[j] = f2bf(1.f / (1.f + __expf(-(v8[j] + ubv[j]))));
            *(u16x8*)&zgb[(size_t)(m0 + half * 64 + row) * 512 + gcol] = o;
        }
    }
}

// ================= gr: [X|H] @ Wr^T -> rgh = bf16(sigmoid * h) =================
__global__ __launch_bounds__(256, 4) void gr_k(
    const u16* __restrict__ Xb, const u16* __restrict__ Hb, const u16* __restrict__ Wt,
    const float* __restrict__ rb_, u16* __restrict__ rgh) {
    __shared__ u16 lds[2 * 8192];
    int tid = threadIdx.x;
    int l = tid & 63, w = tid >> 6;
    int wr = w >> 1, wc = w & 1;
    int swz = (blockIdx.x & 7) * 64 + (blockIdx.x >> 3);
    int mb = swz >> 2, nb = swz & 3;
    int m0 = mb * 128, n0 = nb * 128;
    f32x4 acc[4][4];
#pragma unroll
    for (int m = 0; m < 4; ++m)
#pragma unroll
        for (int n = 0; n < 4; ++n) acc[m][n] = (f32x4){0.f, 0.f, 0.f, 0.f};

    auto ga = [&](int t) -> const u16* {
        return (t < 16) ? (Xb + (size_t)m0 * 512 + t * 32)
                        : (Hb + (size_t)m0 * 512 + (t - 16) * 32);
    };
    auto gb = [&](int t) -> const u16* { return Wt + (size_t)n0 * 1024 + t * 32; };
    kloop32(ga, gb, lds, tid, wr, wc, l, acc);

    float* tf = (float*)lds;
#pragma unroll
    for (int half = 0; half < 2; ++half) {
        __syncthreads();
        if (wr == half) scatter_half(tf, acc, wc, l);
        __syncthreads();
#pragma unroll
        for (int it = 0; it < 4; ++it) {
            int chunk = it * 256 + tid;
            int row = chunk >> 4;
            int c8 = (chunk & 15) << 3;
            f32x8 v8 = *(const f32x8*)&tf[row * 128 + c8];
            int gcol = n0 + c8;
            size_t gbase = (size_t)(m0 + half * 64 + row) * 512 + gcol;
            f32x8 rbv = *(const f32x8*)&rb_[gcol];
            u16x8 h8 = *(const u16x8*)&Hb[gbase];
            u16x8 o;
#pragma unroll
            for (int j = 0; j < 8; ++j) {
                float s = 1.f / (1.f + __expf(-(v8[j] + rbv[j])));
                o[j] = f2bf(s * bf2f(h8[j]));
            }
            *(u16x8*)&rgh[gbase] = o;
        }
    }
}

// ================= gh: [X|rgh] @ Wh^T -> out fp32 =================
__global__ __launch_bounds__(256, 4) void gh_k(
    const u16* __restrict__ Xb, const u16* __restrict__ rgh, const u16* __restrict__ Wt,
    const float* __restrict__ hp, const u16* __restrict__ zgb, const float* __restrict__ hb,
    float* __restrict__ out) {
    __shared__ u16 lds[2 * 8192];
    int tid = threadIdx.x;
    int l = tid & 63, w = tid >> 6;
    int wr = w >> 1, wc = w & 1;
    int swz = (blockIdx.x & 7) * 64 + (blockIdx.x >> 3);
    int mb = swz >> 2, nb = swz & 3;
    int m0 = mb * 128, n0 = nb * 128;
    f32x4 acc[4][4];
#pragma unroll
    for (int m = 0; m < 4; ++m)
#pragma unroll
        for (int n = 0; n < 4; ++n) acc[m][n] = (f32x4){0.f, 0.f, 0.f, 0.f};

    auto ga = [&](int t) -> const u16* {
        return (t < 16) ? (Xb + (size_t)m0 * 512 + t * 32)
                        : (rgh + (size_t)m0 * 512 + (t - 16) * 32);
    };
    auto gb = [&](int t) -> const u16* { return Wt + (size_t)n0 * 1024 + t * 32; };
    kloop32(ga, gb, lds, tid, wr, wc, l, acc);

    float* tf = (float*)lds;
#pragma unroll
    for (int half = 0; half < 2; ++half) {
        __syncthreads();
        if (wr == half) scatter_half(tf, acc, wc, l);
        __syncthreads();
#pragma unroll
        for (int it = 0; it < 4; ++it) {
            int chunk = it * 256 + tid;
            int row = chunk >> 4;
            int c8 = (chunk & 15) << 3;
            f32x8 v8 = *(const f32x8*)&tf[row * 128 + c8];
            int gcol = n0 + c8;
            size_t gbase = (size_t)(m0 + half * 64 + row) * 512 + gcol;
            f32x8 hbv = *(const f32x8*)&hb[gcol];
            f32x8 h8 = *(const f32x8*)&hp[gbase];
            u16x8 z8 = *(const u16x8*)&zgb[gbase];
            f32x8 o;
#pragma unroll
            for (int j = 0; j < 8; ++j) {
                float t = fast_tanh(v8[j] + hbv[j]);
                float z = bf2f(z8[j]);
                o[j] = h8[j] + z * (t - h8[j]);
            }
            *(f32x8*)&out[gbase] = o;
        }
    }
}

extern "C" void kernel_launch(void* const* d_in, const int* in_sizes, int n_in,
                              void* d_out, int out_size, void* d_ws, size_t ws_size,
                              hipStream_t stream) {
    const float* x  = (const float*)d_in[0];
    const float* h  = (const float*)d_in[1];
    const float* wz = (const float*)d_in[2];
    const float* wr = (const float*)d_in[3];
    const float* wh = (const float*)d_in[4];
    const float* ub = (const float*)d_in[5];
    const float* rb = (const float*)d_in[6];
    const float* hb = (const float*)d_in[7];
    float* out = (float*)d_out;

    const int B = 16384;
    char* ws = (char*)d_ws;
    size_t off = 0;
    u16* Xb  = (u16*)(ws + off); off += (size_t)B * 512 * 2;      // 16 MB
    u16* Hb  = (u16*)(ws + off); off += (size_t)B * 512 * 2;      // 16 MB
    u16* Wzt = (u16*)(ws + off); off += (size_t)512 * 1024 * 2;   // 1 MB
    u16* Wrt = (u16*)(ws + off); off += (size_t)512 * 1024 * 2;   // 1 MB
    u16* Wht = (u16*)(ws + off); off += (size_t)512 * 1024 * 2;   // 1 MB
    u16* rgh = (u16*)(ws + off); off += (size_t)B * 512 * 2;      // 16 MB
    u16* zgb = (u16*)(ws + off); off += (size_t)B * 512 * 2;      // 16 MB

    prep_k<<<2048 + 1536, 256, 0, stream>>>(x, h, wz, wr, wh, Xb, Hb, Wzt, Wrt, Wht);

    gz_k<<<512, 256, 0, stream>>>(Xb, Hb, Wzt, ub, zgb);
    gr_k<<<512, 256, 0, stream>>>(Xb, Hb, Wrt, rb, rgh);
    gh_k<<<512, 256, 0, stream>>>(Xb, rgh, Wht, h, zgb, hb, out);
}

// Round 9
// 98.665 us; speedup vs baseline: 1.0011x; 1.0011x over previous
//
#include <hip/hip_runtime.h>
#include <hip/hip_bf16.h>
#include <math.h>

typedef __attribute__((ext_vector_type(4))) float f32x4;
typedef __attribute__((ext_vector_type(8))) float f32x8;
typedef __bf16 bf16x8 __attribute__((ext_vector_type(8)));
typedef unsigned short u16;
typedef u16 u16x8 __attribute__((ext_vector_type(8)));
typedef void __attribute__((address_space(1))) * as1p;
typedef void __attribute__((address_space(3))) * as3p;

// counted waits (T4): NEVER vmcnt(0) in the steady-state loop
#define WAITVM8() asm volatile("s_waitcnt vmcnt(8)" ::: "memory")
#define WAITVM4() asm volatile("s_waitcnt vmcnt(4)" ::: "memory")
#define WAITVM0() asm volatile("s_waitcnt vmcnt(0)" ::: "memory")
#define SBAR()    __builtin_amdgcn_s_barrier()
#define SCHEDB()  __builtin_amdgcn_sched_barrier(0)

__device__ __forceinline__ unsigned short f2bf(float f) {
    union { float f; unsigned int u; } v; v.f = f;
    unsigned int u = v.u;
    u += 0x7fffu + ((u >> 16) & 1u);   // RNE
    return (unsigned short)(u >> 16);
}

__device__ __forceinline__ float bf2f(unsigned short b) {
    union { unsigned int u; float f; } v;
    v.u = ((unsigned int)b) << 16;
    return v.f;
}

__device__ __forceinline__ float fast_tanh(float v) {
    float vc = fminf(fmaxf(v, -15.f), 15.f);
    float e = __expf(2.f * vc);
    return (e - 1.f) / (e + 1.f);
}

// ---------- fused prepass: cvt x,h -> bf16  AND  3 weight transposes ----------
__global__ void prep_k(const float* __restrict__ x, const float* __restrict__ h,
                       const float* __restrict__ wz, const float* __restrict__ wrr,
                       const float* __restrict__ wh,
                       u16* __restrict__ xb, u16* __restrict__ hb,
                       u16* __restrict__ wzt, u16* __restrict__ wrt, u16* __restrict__ wht) {
    __shared__ float t[32][33];
    int bid = blockIdx.x;
    int tid = threadIdx.x;
    if (bid < 2048) {
        const int n4 = 16384 * 512 / 4;
        int i = bid * 256 + tid;
        const int stride = 2048 * 256;
        const float4* x4 = (const float4*)x;
        const float4* h4 = (const float4*)h;
        ushort4* xb4 = (ushort4*)xb;
        ushort4* hb4 = (ushort4*)hb;
        for (; i < n4; i += stride) {
            float4 v = x4[i];
            xb4[i] = make_ushort4(f2bf(v.x), f2bf(v.y), f2bf(v.z), f2bf(v.w));
            float4 w = h4[i];
            hb4[i] = make_ushort4(f2bf(w.x), f2bf(w.y), f2bf(w.z), f2bf(w.w));
        }
    } else {
        int b = bid - 2048;
        int z = b >> 9;
        int rem = b & 511;
        const float* src = (z == 0) ? wz : (z == 1) ? wrr : wh;
        u16* dst = (z == 0) ? wzt : (z == 1) ? wrt : wht;
        int n0 = (rem & 15) * 32;
        int k0 = (rem >> 4) * 32;
        int tx = tid & 31, ty = tid >> 5;
#pragma unroll
        for (int i = 0; i < 4; ++i)
            t[ty + i * 8][tx] = src[(size_t)(k0 + ty + i * 8) * 512 + n0 + tx];
        __syncthreads();
#pragma unroll
        for (int i = 0; i < 4; ++i)
            dst[(size_t)(n0 + ty + i * 8) * 1024 + k0 + tx] = f2bf(t[tx][ty + i * 8]);
    }
}

// ---------- BK=32 staging: 128x32 bf16 (8 KB), linear LDS dest, inverse-swizzled src ----------
__device__ __forceinline__ void stage32(const u16* g, int gstride, u16* region, int tid) {
#pragma unroll
    for (int i = 0; i < 2; ++i) {
        int ob = i * 4096 + ((tid >> 6) << 10);     // wave-uniform byte base
        int o = ob + ((tid & 63) << 4);
        int row = o >> 6;
        int cb = (o & 63) ^ ((row & 3) << 4);       // inverse swizzle (16B chunks)
        const u16* gp = g + (size_t)row * gstride + (cb >> 1);
        __builtin_amdgcn_global_load_lds((as1p)(void*)gp, (as3p)(void*)(region + (ob >> 1)), 16, 0, 0);
    }
}

__device__ __forceinline__ bf16x8 ld32(const u16* region, int r, int kb) {
    int byte = (r << 6) + (kb ^ ((r & 3) << 4));
    return *(const bf16x8*)((const char*)region + byte);
}

// ---------- one BK=32 step: 8 swizzled ds_read_b128 + 16 MFMA ----------
__device__ __forceinline__ void compute32(const u16* LA, const u16* LB,
                                          int wr, int wc, int l, f32x4 (&acc)[4][4]) {
    int fr = l & 15;
    int kbb = (l >> 4) << 4;
    bf16x8 a[4], b[4];
#pragma unroll
    for (int m = 0; m < 4; ++m)
        a[m] = ld32(LA, wr * 64 + m * 16 + fr, kbb);
#pragma unroll
    for (int n = 0; n < 4; ++n)
        b[n] = ld32(LB, wc * 64 + n * 16 + fr, kbb);
#pragma unroll
    for (int m = 0; m < 4; ++m)
#pragma unroll
        for (int n = 0; n < 4; ++n)
            acc[m][n] = __builtin_amdgcn_mfma_f32_16x16x32_bf16(a[m], b[n], acc[m][n], 0, 0, 0);
}

// ---------- 4-buffer ring K-loop, counted vmcnt, raw s_barrier (T3+T4) ----------
// buf b: A at lds + b*8192, B at lds + b*8192 + 4096 (u16 offsets). 64 KB total.
// Per tile: 4 global_load_lds per thread (2 A + 2 B). Steady state: 3 tiles in flight.
template<typename AF, typename BF>
__device__ __forceinline__ void kring(AF ga, BF gb, u16* lds, int tid,
                                      int wr, int wc, int l, f32x4 (&acc)[4][4]) {
#pragma unroll
    for (int t = 0; t < 3; ++t) {
        u16* b = lds + t * 8192;
        stage32(ga(t), 512, b, tid);
        stage32(gb(t), 1024, b + 4096, tid);
    }
#pragma unroll
    for (int i = 0; i < 29; ++i) {
        WAITVM8(); SCHEDB();   // tile i landed; tiles i+1,i+2 stay in flight
        SBAR(); SCHEDB();      // all waves: tile i complete, compute(i-1) done
        u16* nb_ = lds + ((i + 3) & 3) * 8192;   // == buf (i-1)&3, now free
        stage32(ga(i + 3), 512, nb_, tid);
        stage32(gb(i + 3), 1024, nb_ + 4096, tid);
        const u16* cur = lds + (i & 3) * 8192;
        compute32(cur, cur + 4096, wr, wc, l, acc);
    }
    // tail: i=29 (tiles 30,31 in flight), i=30 (31 in flight), i=31 (none)
    WAITVM8(); SCHEDB(); SBAR(); SCHEDB();
    { const u16* cur = lds + (29 & 3) * 8192; compute32(cur, cur + 4096, wr, wc, l, acc); }
    WAITVM4(); SCHEDB(); SBAR(); SCHEDB();
    { const u16* cur = lds + (30 & 3) * 8192; compute32(cur, cur + 4096, wr, wc, l, acc); }
    WAITVM0(); SCHEDB(); SBAR(); SCHEDB();
    { const u16* cur = lds + (31 & 3) * 8192; compute32(cur, cur + 4096, wr, wc, l, acc); }
}

// ---------- scatter one 64-row half of acc into f32 [64][128] LDS tile ----------
__device__ __forceinline__ void scatter_half(float* tf, const f32x4 (&acc)[4][4],
                                             int wc, int l) {
    int colb = wc * 64;
    int rowb = (l >> 4) << 2;
#pragma unroll
    for (int n = 0; n < 4; ++n) {
        int col = colb + n * 16 + (l & 15);
#pragma unroll
        for (int m = 0; m < 4; ++m) {
            int row0 = rowb + m * 16;
#pragma unroll
            for (int r = 0; r < 4; ++r)
                tf[(row0 + r) * 128 + col] = acc[m][n][r];
        }
    }
}

// ================= zr: [X|H] @ [Wz|Wr]^T (N=1024, 1024 blocks) -> zgb / rgh =================
__global__ __launch_bounds__(256, 2) void zr_k(
    const u16* __restrict__ Xb, const u16* __restrict__ Hb,
    const u16* __restrict__ Wzt, const u16* __restrict__ Wrt,
    const float* __restrict__ ub, const float* __restrict__ rb_,
    u16* __restrict__ zgb, u16* __restrict__ rgh) {
    __shared__ u16 lds[4 * 8192];
    int tid = threadIdx.x;
    int l = tid & 63, w = tid >> 6;
    int wr = w >> 1, wc = w & 1;
    int swz = (blockIdx.x & 7) * 128 + (blockIdx.x >> 3);   // bijective XCD swizzle
    int mb = swz >> 3, nb = swz & 7;
    int m0 = mb * 128, n0 = nb * 128;
    bool isZ = (n0 < 512);
    const u16* Wt = isZ ? Wzt : Wrt;
    int nw = isZ ? n0 : (n0 - 512);                          // col base within gate

    f32x4 acc[4][4];
#pragma unroll
    for (int m = 0; m < 4; ++m)
#pragma unroll
        for (int n = 0; n < 4; ++n) acc[m][n] = (f32x4){0.f, 0.f, 0.f, 0.f};

    auto ga = [&](int t) -> const u16* {
        return (t < 16) ? (Xb + (size_t)m0 * 512 + t * 32)
                        : (Hb + (size_t)m0 * 512 + (t - 16) * 32);
    };
    auto gb = [&](int t) -> const u16* { return Wt + (size_t)nw * 1024 + t * 32; };
    kring(ga, gb, lds, tid, wr, wc, l, acc);

    float* tf = (float*)lds;
#pragma unroll
    for (int half = 0; half < 2; ++half) {
        __syncthreads();
        if (wr == half) scatter_half(tf, acc, wc, l);
        __syncthreads();
#pragma unroll
        for (int it = 0; it < 4; ++it) {
            int chunk = it * 256 + tid;
            int row = chunk >> 4;
            int c8 = (chunk & 15) << 3;
            f32x8 v8 = *(const f32x8*)&tf[row * 128 + c8];
            int gcol = nw + c8;
            size_t gbase = (size_t)(m0 + half * 64 + row) * 512 + gcol;
            if (isZ) {
                f32x8 bv = *(const f32x8*)&ub[gcol];
                u16x8 o;
#pragma unroll
                for (int j = 0; j < 8; ++j)
                    o[j] = f2bf(1.f / (1.f + __expf(-(v8[j] + bv[j]))));
                *(u16x8*)&zgb[gbase] = o;
            } else {
                f32x8 bv = *(const f32x8*)&rb_[gcol];
                u16x8 h8 = *(const u16x8*)&Hb[gbase];
                u16x8 o;
#pragma unroll
                for (int j = 0; j < 8; ++j) {
                    float s = 1.f / (1.f + __expf(-(v8[j] + bv[j])));
                    o[j] = f2bf(s * bf2f(h8[j]));
                }
                *(u16x8*)&rgh[gbase] = o;
            }
        }
    }
}

// ================= gh: [X|rgh] @ Wh^T -> out fp32 (512 blocks) =================
__global__ __launch_bounds__(256, 2) void gh_k(
    const u16* __restrict__ Xb, const u16* __restrict__ rgh, const u16* __restrict__ Wt,
    const float* __restrict__ hp, const u16* __restrict__ zgb, const float* __restrict__ hb,
    float* __restrict__ out) {
    __shared__ u16 lds[4 * 8192];
    int tid = threadIdx.x;
    int l = tid & 63, w = tid >> 6;
    int wr = w >> 1, wc = w & 1;
    int swz = (blockIdx.x & 7) * 64 + (blockIdx.x >> 3);
    int mb = swz >> 2, nb = swz & 3;
    int m0 = mb * 128, n0 = nb * 128;
    f32x4 acc[4][4];
#pragma unroll
    for (int m = 0; m < 4; ++m)
#pragma unroll
        for (int n = 0; n < 4; ++n) acc[m][n] = (f32x4){0.f, 0.f, 0.f, 0.f};

    auto ga = [&](int t) -> const u16* {
        return (t < 16) ? (Xb + (size_t)m0 * 512 + t * 32)
                        : (rgh + (size_t)m0 * 512 + (t - 16) * 32);
    };
    auto gb = [&](int t) -> const u16* { return Wt + (size_t)n0 * 1024 + t * 32; };
    kring(ga, gb, lds, tid, wr, wc, l, acc);

    float* tf = (float*)lds;
#pragma unroll
    for (int half = 0; half < 2; ++half) {
        __syncthreads();
        if (wr == half) scatter_half(tf, acc, wc, l);
        __syncthreads();
#pragma unroll
        for (int it = 0; it < 4; ++it) {
            int chunk = it * 256 + tid;
            int row = chunk >> 4;
            int c8 = (chunk & 15) << 3;
            f32x8 v8 = *(const f32x8*)&tf[row * 128 + c8];
            int gcol = n0 + c8;
            size_t gbase = (size_t)(m0 + half * 64 + row) * 512 + gcol;
            f32x8 hbv = *(const f32x8*)&hb[gcol];
            f32x8 h8 = *(const f32x8*)&hp[gbase];
            u16x8 z8 = *(const u16x8*)&zgb[gbase];
            f32x8 o;
#pragma unroll
            for (int j = 0; j < 8; ++j) {
                float t = fast_tanh(v8[j] + hbv[j]);
                float z = bf2f(z8[j]);
                o[j] = h8[j] + z * (t - h8[j]);
            }
            *(f32x8*)&out[gbase] = o;
        }
    }
}

extern "C" void kernel_launch(void* const* d_in, const int* in_sizes, int n_in,
                              void* d_out, int out_size, void* d_ws, size_t ws_size,
                              hipStream_t stream) {
    const float* x  = (const float*)d_in[0];
    const float* h  = (const float*)d_in[1];
    const float* wz = (const float*)d_in[2];
    const float* wr = (const float*)d_in[3];
    const float* wh = (const float*)d_in[4];
    const float* ub = (const float*)d_in[5];
    const float* rb = (const float*)d_in[6];
    const float* hb = (const float*)d_in[7];
    float* out = (float*)d_out;

    const int B = 16384;
    char* ws = (char*)d_ws;
    size_t off = 0;
    u16* Xb  = (u16*)(ws + off); off += (size_t)B * 512 * 2;      // 16 MB
    u16* Hb  = (u16*)(ws + off); off += (size_t)B * 512 * 2;      // 16 MB
    u16* Wzt = (u16*)(ws + off); off += (size_t)512 * 1024 * 2;   // 1 MB
    u16* Wrt = (u16*)(ws + off); off += (size_t)512 * 1024 * 2;   // 1 MB
    u16* Wht = (u16*)(ws + off); off += (size_t)512 * 1024 * 2;   // 1 MB
    u16* rgh = (u16*)(ws + off); off += (size_t)B * 512 * 2;      // 16 MB
    u16* zgb = (u16*)(ws + off); off += (size_t)B * 512 * 2;      // 16 MB

    prep_k<<<2048 + 1536, 256, 0, stream>>>(x, h, wz, wr, wh, Xb, Hb, Wzt, Wrt, Wht);

    zr_k<<<1024, 256, 0, stream>>>(Xb, Hb, Wzt, Wrt, ub, rb, zgb, rgh);
    gh_k<<<512, 256, 0, stream>>>(Xb, rgh, Wht, h, zgb, hb, out);
}